// Round 8
// baseline (236.689 us; speedup 1.0000x reference)
//
#include <hip/hip_runtime.h>
#include <hip/hip_cooperative_groups.h>

namespace cg = cooperative_groups;

#define NB    32      // batch
#define CIN   512     // IN_CH
#define MID2  1024    // MAX_MID*2
#define MID   512     // MAX_MID
#define HW    4096    // 64*64

#define NBLK  512     // cooperative grid: 512 blocks x 256 thr = 2048 waves
                      // needs only 2 blocks/CU co-resident (VGPR<=128, LDS 2KB)

typedef float f32x4 __attribute__((ext_vector_type(4)));

// ---------------- Cooperative single-kernel path ----------------
// GAP -> sync -> fc1 -> sync -> fc2 -> sync -> mask. grid.sync() carries the
// device-scope fence needed across XCDs (G16). All FP orders fixed.
__global__ __launch_bounds__(256, 4) void k_all(const float* __restrict__ x,
                                                const float* __restrict__ w1,
                                                const float* __restrict__ b1,
                                                const float* __restrict__ w2,
                                                const float* __restrict__ b2,
                                                float* __restrict__ out,
                                                float* __restrict__ gap,
                                                float* __restrict__ h,
                                                float* __restrict__ scores) {
    cg::grid_group grid = cg::this_grid();
    const int wid = threadIdx.x >> 6, lane = threadIdx.x & 63;
    const int wId = blockIdx.x * 4 + wid;             // 0 .. 2047

    // ---- Phase 1: global average pool (8 rows per wave, serial rows,
    //      16 independent nontemporal float4 loads in flight per row) ----
#pragma unroll 1
    for (int rr = 0; rr < 8; ++rr) {
        const int row = wId * 8 + rr;                 // 0 .. 16383
        const f32x4* p = (const f32x4*)(x + (size_t)row * HW);
        float s0 = 0.f, s1 = 0.f, s2 = 0.f, s3 = 0.f;
#pragma unroll
        for (int i = 0; i < 4; ++i) {
            f32x4 a = __builtin_nontemporal_load(&p[(4 * i + 0) * 64 + lane]);
            f32x4 b = __builtin_nontemporal_load(&p[(4 * i + 1) * 64 + lane]);
            f32x4 c = __builtin_nontemporal_load(&p[(4 * i + 2) * 64 + lane]);
            f32x4 d = __builtin_nontemporal_load(&p[(4 * i + 3) * 64 + lane]);
            s0 += (a.x + a.y) + (a.z + a.w);
            s1 += (b.x + b.y) + (b.z + b.w);
            s2 += (c.x + c.y) + (c.z + c.w);
            s3 += (d.x + d.y) + (d.z + d.w);
        }
        float s = (s0 + s1) + (s2 + s3);
        for (int off = 32; off; off >>= 1) s += __shfl_down(s, off, 64);
        if (lane == 0) gap[row] = s * (1.0f / HW);
    }
    grid.sync();

    // ---- Phase 2: fc1 + ReLU (16 outputs per wave, gap slice in regs) ----
    {
        const int o0 = wId * 16;                      // 0 .. 32752
        const int b  = o0 >> 10;
        const int j0 = o0 & (MID2 - 1);
        const float* g = gap + b * CIN + lane * 8;
        const float4 g0 = *(const float4*)g;
        const float4 g1 = *(const float4*)(g + 4);
        float s[16];
#pragma unroll
        for (int r = 0; r < 16; ++r) {
            const float* w = w1 + (size_t)(j0 + r) * CIN + lane * 8;
            const float4 a = *(const float4*)w;
            const float4 c = *(const float4*)(w + 4);
            s[r] = (a.x * g0.x + a.y * g0.y) + (a.z * g0.z + a.w * g0.w) +
                   (c.x * g1.x + c.y * g1.y) + (c.z * g1.z + c.w * g1.w);
        }
#pragma unroll
        for (int r = 0; r < 16; ++r)
            for (int off = 32; off; off >>= 1) s[r] += __shfl_down(s[r], off, 64);
        if (lane == 0) {
#pragma unroll
            for (int r = 0; r < 16; ++r) h[o0 + r] = fmaxf(s[r] + b1[j0 + r], 0.f);
        }
    }
    grid.sync();

    // ---- Phase 3: fc2 + sigmoid (8 outputs per wave, h slice in regs) ----
    {
        const int o0 = wId * 8;                       // 0 .. 16376
        const int b  = o0 >> 9;
        const int m0 = o0 & (MID - 1);
        const float4* h4 = (const float4*)(h + b * MID2 + lane * 16);
        const float4 h0 = h4[0], h1 = h4[1], h2 = h4[2], h3 = h4[3];
        float s[8];
#pragma unroll
        for (int r = 0; r < 8; ++r) {
            const float4* w = (const float4*)(w2 + (size_t)(m0 + r) * MID2 + lane * 16);
            const float4 a = w[0], c = w[1], d = w[2], e = w[3];
            s[r] = (a.x * h0.x + a.y * h0.y) + (a.z * h0.z + a.w * h0.w) +
                   (c.x * h1.x + c.y * h1.y) + (c.z * h1.z + c.w * h1.w) +
                   (d.x * h2.x + d.y * h2.y) + (d.z * h2.z + d.w * h2.w) +
                   (e.x * h3.x + e.y * h3.y) + (e.z * h3.z + e.w * h3.w);
        }
#pragma unroll
        for (int r = 0; r < 8; ++r)
            for (int off = 32; off; off >>= 1) s[r] += __shfl_down(s[r], off, 64);
        if (lane == 0) {
#pragma unroll
            for (int r = 0; r < 8; ++r) {
                const float v = s[r] + b2[m0 + r];
                scores[o0 + r] = 1.0f / (1.0f + __expf(-v));
            }
        }
    }
    grid.sync();

    // ---- Phase 4: mean -> k -> threshold -> mask (blocks 0..31 only) ----
    const int b = blockIdx.x;
    if (b >= NB) return;
    const int t = threadIdx.x;
    __shared__ float srow[MID];
    __shared__ float red[4];
    __shared__ float thr;

    float s = 0.f;
#pragma unroll
    for (int i = 0; i < NB * MID / 256; ++i) s += scores[i * 256 + t];
    for (int off = 32; off; off >>= 1) s += __shfl_down(s, off, 64);
    if (lane == 0) red[wid] = s;

    const float v0 = scores[b * MID + t];
    const float v1 = scores[b * MID + t + 256];
    srow[t]       = v0;
    srow[t + 256] = v1;
    __syncthreads();

    const float tot = (red[0] + red[1]) + (red[2] + red[3]);
    const float mean = tot / (float)(NB * MID);
    const float scale = fminf(fmaxf(mean, 0.25f), 1.0f);
    int k = (int)ceilf((float)MID * scale);
    k = min(max(k, 128), MID);                        // k_min = max(4, 512/4) = 128

    const float4* srow4 = (const float4*)srow;
    int gt0 = 0, ge0 = 0, gt1 = 0, ge1 = 0;
    for (int i = 0; i < MID / 4; ++i) {
        const float4 u = srow4[i];    // uniform addr -> LDS broadcast
        gt0 += (u.x > v0) + (u.y > v0) + (u.z > v0) + (u.w > v0);
        ge0 += (u.x >= v0) + (u.y >= v0) + (u.z >= v0) + (u.w >= v0);
        gt1 += (u.x > v1) + (u.y > v1) + (u.z > v1) + (u.w > v1);
        ge1 += (u.x >= v1) + (u.y >= v1) + (u.z >= v1) + (u.w >= v1);
    }
    if (gt0 < k && ge0 >= k) thr = v0;  // tie-safe kth-largest selection
    if (gt1 < k && ge1 >= k) thr = v1;
    __syncthreads();
    out[b * MID + t]       = (v0 >= thr) ? 1.0f : 0.0f;
    out[b * MID + t + 256] = (v1 >= thr) ? 1.0f : 0.0f;
    if (b == 0 && t == 0) out[NB * MID] = (float)k;
}

// ================= Fallback chain (R6, known-good 67 us) =================
__global__ __launch_bounds__(256, 8) void k_gap(const float* __restrict__ x,
                                                float* __restrict__ gap) {
    const int r0 = blockIdx.x * 2;
    const int t  = threadIdx.x;
    const f32x4* p0 = (const f32x4*)(x + (size_t)r0 * HW);
    const f32x4* p1 = (const f32x4*)(x + (size_t)(r0 + 1) * HW);
    float a0 = 0.f, a1 = 0.f;
#pragma unroll
    for (int i = 0; i < 4; ++i) {
        f32x4 u = __builtin_nontemporal_load(&p0[i * 256 + t]);
        f32x4 v = __builtin_nontemporal_load(&p1[i * 256 + t]);
        a0 += (u.x + u.y) + (u.z + u.w);
        a1 += (v.x + v.y) + (v.z + v.w);
    }
    for (int off = 32; off; off >>= 1) {
        a0 += __shfl_down(a0, off, 64);
        a1 += __shfl_down(a1, off, 64);
    }
    __shared__ float w0[4], w1[4];
    const int wid = t >> 6, lane = t & 63;
    if (lane == 0) { w0[wid] = a0; w1[wid] = a1; }
    __syncthreads();
    if (t == 0) gap[r0]     = ((w0[0] + w0[1]) + (w0[2] + w0[3])) * (1.0f / HW);
    if (t == 1) gap[r0 + 1] = ((w1[0] + w1[1]) + (w1[2] + w1[3])) * (1.0f / HW);
}

__global__ __launch_bounds__(256) void k_fc1(const float* __restrict__ gap,
                                             const float* __restrict__ w1,
                                             const float* __restrict__ b1,
                                             float* __restrict__ h) {
    const int wid = threadIdx.x >> 6, lane = threadIdx.x & 63;
    const int o4 = (blockIdx.x * 4 + wid) * 4;
    const int b  = o4 >> 10;
    const int j0 = o4 & (MID2 - 1);
    const float* g = gap + b * CIN + lane * 8;
    const float4 g0 = *(const float4*)g;
    const float4 g1 = *(const float4*)(g + 4);
    float s[4];
#pragma unroll
    for (int r = 0; r < 4; ++r) {
        const float* w = w1 + (size_t)(j0 + r) * CIN + lane * 8;
        const float4 a = *(const float4*)w;
        const float4 c = *(const float4*)(w + 4);
        s[r] = (a.x * g0.x + a.y * g0.y) + (a.z * g0.z + a.w * g0.w) +
               (c.x * g1.x + c.y * g1.y) + (c.z * g1.z + c.w * g1.w);
    }
#pragma unroll
    for (int r = 0; r < 4; ++r)
        for (int off = 32; off; off >>= 1) s[r] += __shfl_down(s[r], off, 64);
    if (lane == 0) {
#pragma unroll
        for (int r = 0; r < 4; ++r) h[o4 + r] = fmaxf(s[r] + b1[j0 + r], 0.f);
    }
}

__global__ __launch_bounds__(256) void k_fc2(const float* __restrict__ h,
                                             const float* __restrict__ w2,
                                             const float* __restrict__ b2,
                                             float* __restrict__ scores) {
    const int wid = threadIdx.x >> 6, lane = threadIdx.x & 63;
    const int o4 = (blockIdx.x * 4 + wid) * 4;
    const int b  = o4 >> 9;
    const int m0 = o4 & (MID - 1);
    const float4* h4 = (const float4*)(h + b * MID2 + lane * 16);
    const float4 h0 = h4[0], h1 = h4[1], h2 = h4[2], h3 = h4[3];
    float s[4];
#pragma unroll
    for (int r = 0; r < 4; ++r) {
        const float4* w = (const float4*)(w2 + (size_t)(m0 + r) * MID2 + lane * 16);
        const float4 a = w[0], c = w[1], d = w[2], e = w[3];
        s[r] = (a.x * h0.x + a.y * h0.y) + (a.z * h0.z + a.w * h0.w) +
               (c.x * h1.x + c.y * h1.y) + (c.z * h1.z + c.w * h1.w) +
               (d.x * h2.x + d.y * h2.y) + (d.z * h2.z + d.w * h2.w) +
               (e.x * h3.x + e.y * h3.y) + (e.z * h3.z + e.w * h3.w);
    }
#pragma unroll
    for (int r = 0; r < 4; ++r)
        for (int off = 32; off; off >>= 1) s[r] += __shfl_down(s[r], off, 64);
    if (lane == 0) {
#pragma unroll
        for (int r = 0; r < 4; ++r) {
            const float v = s[r] + b2[m0 + r];
            scores[o4 + r] = 1.0f / (1.0f + __expf(-v));
        }
    }
}

__global__ __launch_bounds__(512) void k_mask(const float* __restrict__ scores,
                                              float* __restrict__ out) {
    __shared__ float srow[MID];
    __shared__ float red[8];
    __shared__ float thr;
    const int b = blockIdx.x, t = threadIdx.x;

    float s = 0.f;
#pragma unroll
    for (int i = 0; i < NB * MID / 512; ++i) s += scores[i * 512 + t];
    for (int off = 32; off; off >>= 1) s += __shfl_down(s, off, 64);
    const int wid = t >> 6, lane = t & 63;
    if (lane == 0) red[wid] = s;

    const float v = scores[b * MID + t];
    srow[t] = v;
    __syncthreads();

    const float tot = ((red[0] + red[1]) + (red[2] + red[3])) +
                      ((red[4] + red[5]) + (red[6] + red[7]));
    const float mean = tot / (float)(NB * MID);
    const float scale = fminf(fmaxf(mean, 0.25f), 1.0f);
    int k = (int)ceilf((float)MID * scale);
    k = min(max(k, 128), MID);

    const float4* srow4 = (const float4*)srow;
    int gt = 0, ge = 0;
    for (int i = 0; i < MID / 4; ++i) {
        const float4 u = srow4[i];
        gt += (u.x > v) + (u.y > v) + (u.z > v) + (u.w > v);
        ge += (u.x >= v) + (u.y >= v) + (u.z >= v) + (u.w >= v);
    }
    if (gt < k && ge >= k) thr = v;
    __syncthreads();
    out[b * MID + t] = (v >= thr) ? 1.0f : 0.0f;
    if (b == 0 && t == 0) out[NB * MID] = (float)k;
}

extern "C" void kernel_launch(void* const* d_in, const int* in_sizes, int n_in,
                              void* d_out, int out_size, void* d_ws, size_t ws_size,
                              hipStream_t stream) {
    const float* x  = (const float*)d_in[0];
    const float* w1 = (const float*)d_in[1];
    const float* b1 = (const float*)d_in[2];
    const float* w2 = (const float*)d_in[3];
    const float* b2 = (const float*)d_in[4];
    float* out = (float*)d_out;

    float* gap    = (float*)d_ws;            // NB*CIN  = 16384 floats
    float* h      = gap + NB * CIN;          // NB*MID2 = 32768 floats
    float* scores = h + NB * MID2;           // NB*MID  = 16384 floats

    // Capture-safe host queries to decide if the cooperative path is viable.
    int dev = 0;
    hipGetDevice(&dev);
    int coop = 0, ncu = 0, maxb = 0;
    hipDeviceGetAttribute(&coop, hipDeviceAttributeCooperativeLaunch, dev);
    hipDeviceGetAttribute(&ncu, hipDeviceAttributeMultiprocessorCount, dev);
    hipOccupancyMaxActiveBlocksPerMultiprocessor(&maxb, (const void*)k_all, 256, 0);

    hipError_t ret = hipErrorUnknown;
    if (coop && (long)maxb * ncu >= NBLK) {
        void* args[] = { (void*)&x, (void*)&w1, (void*)&b1, (void*)&w2, (void*)&b2,
                         (void*)&out, (void*)&gap, (void*)&h, (void*)&scores };
        ret = hipLaunchCooperativeKernel((const void*)k_all, dim3(NBLK), dim3(256),
                                         args, 0, stream);
    }
    if (ret != hipSuccess) {
        // Known-good 4-kernel chain fallback.
        k_gap <<<NB * CIN / 2,      256, 0, stream>>>(x, gap);
        k_fc1 <<<NB * MID2 / (4*4), 256, 0, stream>>>(gap, w1, b1, h);
        k_fc2 <<<NB * MID  / (4*4), 256, 0, stream>>>(h, w2, b2, scores);
        k_mask<<<NB,                512, 0, stream>>>(scores, out);
    }
}

// Round 9
// 67.295 us; speedup vs baseline: 3.5172x; 3.5172x over previous
//
#include <hip/hip_runtime.h>
#include <hip/hip_cooperative_groups.h>

namespace cg = cooperative_groups;

#define NB    32      // batch
#define CIN   512     // IN_CH
#define MID2  1024    // MAX_MID*2
#define MID   512     // MAX_MID
#define HW    4096    // 64*64

#define NBLK  2048    // cooperative grid: 2048 blocks x 256 thr = 8 blocks/CU
                      // = 32 waves/CU (full occupancy; VGPR<=64 required)

typedef float f32x4 __attribute__((ext_vector_type(4)));

// ---------------- Cooperative single-kernel path (full occupancy) ----------
// GAP -> sync -> fc1 -> sync -> fc2 -> sync -> mask. grid.sync() carries the
// device-scope fence needed across XCDs (G16). All FP orders fixed.
__global__ __launch_bounds__(256, 8) void k_all(const float* __restrict__ x,
                                                const float* __restrict__ w1,
                                                const float* __restrict__ b1,
                                                const float* __restrict__ w2,
                                                const float* __restrict__ b2,
                                                float* __restrict__ out,
                                                float* __restrict__ gap,
                                                float* __restrict__ h,
                                                float* __restrict__ scores) {
    cg::grid_group grid = cg::this_grid();
    const int t   = threadIdx.x;
    const int wid = t >> 6, lane = t & 63;
    const int wId = blockIdx.x * 4 + wid;             // 0 .. 8191

    __shared__ float w0s[4], w1s[4];
    __shared__ float srow[MID];
    __shared__ float red[4];
    __shared__ float thr;

    // ---- Phase 1: GAP. 8 rows per block, processed as 4 pairs with the
    //      R6 pattern: 8 independent nontemporal float4 loads in flight. ----
    const int r0 = blockIdx.x * 8;
#pragma unroll 1
    for (int pp = 0; pp < 4; ++pp) {
        const int ra = r0 + pp * 2;
        const f32x4* p0 = (const f32x4*)(x + (size_t)ra * HW);
        const f32x4* p1 = (const f32x4*)(x + (size_t)(ra + 1) * HW);
        float a0 = 0.f, a1 = 0.f;
#pragma unroll
        for (int i = 0; i < 4; ++i) {
            f32x4 u = __builtin_nontemporal_load(&p0[i * 256 + t]);
            f32x4 v = __builtin_nontemporal_load(&p1[i * 256 + t]);
            a0 += (u.x + u.y) + (u.z + u.w);
            a1 += (v.x + v.y) + (v.z + v.w);
        }
        for (int off = 32; off; off >>= 1) {
            a0 += __shfl_down(a0, off, 64);
            a1 += __shfl_down(a1, off, 64);
        }
        if (lane == 0) { w0s[wid] = a0; w1s[wid] = a1; }
        __syncthreads();
        if (t == 0) gap[ra]     = ((w0s[0] + w0s[1]) + (w0s[2] + w0s[3])) * (1.0f / HW);
        if (t == 1) gap[ra + 1] = ((w1s[0] + w1s[1]) + (w1s[2] + w1s[3])) * (1.0f / HW);
        __syncthreads();   // w0s/w1s reused next pair
    }
    grid.sync();

    // ---- Phase 2: fc1 + ReLU (4 outputs per wave, gap slice in regs) ----
    {
        const int o0 = wId * 4;                       // 0 .. 32764
        const int b  = o0 >> 10;
        const int j0 = o0 & (MID2 - 1);
        const float* g = gap + b * CIN + lane * 8;
        const float4 g0 = *(const float4*)g;
        const float4 g1 = *(const float4*)(g + 4);
        float s[4];
#pragma unroll
        for (int r = 0; r < 4; ++r) {
            const float* w = w1 + (size_t)(j0 + r) * CIN + lane * 8;
            const float4 a = *(const float4*)w;
            const float4 c = *(const float4*)(w + 4);
            s[r] = (a.x * g0.x + a.y * g0.y) + (a.z * g0.z + a.w * g0.w) +
                   (c.x * g1.x + c.y * g1.y) + (c.z * g1.z + c.w * g1.w);
        }
#pragma unroll
        for (int r = 0; r < 4; ++r)
            for (int off = 32; off; off >>= 1) s[r] += __shfl_down(s[r], off, 64);
        if (lane == 0) {
#pragma unroll
            for (int r = 0; r < 4; ++r) h[o0 + r] = fmaxf(s[r] + b1[j0 + r], 0.f);
        }
    }
    grid.sync();

    // ---- Phase 3: fc2 + sigmoid (2 outputs per wave, h slice in regs) ----
    {
        const int o0 = wId * 2;                       // 0 .. 16382
        const int b  = o0 >> 9;
        const int m0 = o0 & (MID - 1);
        const float4* h4 = (const float4*)(h + b * MID2 + lane * 16);
        const float4 h0 = h4[0], h1 = h4[1], h2 = h4[2], h3 = h4[3];
        float s[2];
#pragma unroll
        for (int r = 0; r < 2; ++r) {
            const float4* w = (const float4*)(w2 + (size_t)(m0 + r) * MID2 + lane * 16);
            const float4 a = w[0], c = w[1], d = w[2], e = w[3];
            s[r] = (a.x * h0.x + a.y * h0.y) + (a.z * h0.z + a.w * h0.w) +
                   (c.x * h1.x + c.y * h1.y) + (c.z * h1.z + c.w * h1.w) +
                   (d.x * h2.x + d.y * h2.y) + (d.z * h2.z + d.w * h2.w) +
                   (e.x * h3.x + e.y * h3.y) + (e.z * h3.z + e.w * h3.w);
        }
#pragma unroll
        for (int r = 0; r < 2; ++r)
            for (int off = 32; off; off >>= 1) s[r] += __shfl_down(s[r], off, 64);
        if (lane == 0) {
#pragma unroll
            for (int r = 0; r < 2; ++r) {
                const float v = s[r] + b2[m0 + r];
                scores[o0 + r] = 1.0f / (1.0f + __expf(-v));
            }
        }
    }
    grid.sync();

    // ---- Phase 4: mean -> k -> threshold -> mask (blocks 0..31 only) ----
    const int b = blockIdx.x;
    if (b >= NB) return;

    float s = 0.f;
#pragma unroll
    for (int i = 0; i < NB * MID / 256; ++i) s += scores[i * 256 + t];
    for (int off = 32; off; off >>= 1) s += __shfl_down(s, off, 64);
    if (lane == 0) red[wid] = s;

    const float v0 = scores[b * MID + t];
    const float v1 = scores[b * MID + t + 256];
    srow[t]       = v0;
    srow[t + 256] = v1;
    __syncthreads();

    const float tot = (red[0] + red[1]) + (red[2] + red[3]);
    const float mean = tot / (float)(NB * MID);
    const float scale = fminf(fmaxf(mean, 0.25f), 1.0f);
    int k = (int)ceilf((float)MID * scale);
    k = min(max(k, 128), MID);                        // k_min = max(4, 512/4) = 128

    const float4* srow4 = (const float4*)srow;
    int gt0 = 0, ge0 = 0, gt1 = 0, ge1 = 0;
    for (int i = 0; i < MID / 4; ++i) {
        const float4 u = srow4[i];    // uniform addr -> LDS broadcast
        gt0 += (u.x > v0) + (u.y > v0) + (u.z > v0) + (u.w > v0);
        ge0 += (u.x >= v0) + (u.y >= v0) + (u.z >= v0) + (u.w >= v0);
        gt1 += (u.x > v1) + (u.y > v1) + (u.z > v1) + (u.w > v1);
        ge1 += (u.x >= v1) + (u.y >= v1) + (u.z >= v1) + (u.w >= v1);
    }
    if (gt0 < k && ge0 >= k) thr = v0;  // tie-safe kth-largest selection
    if (gt1 < k && ge1 >= k) thr = v1;
    __syncthreads();
    out[b * MID + t]       = (v0 >= thr) ? 1.0f : 0.0f;
    out[b * MID + t + 256] = (v1 >= thr) ? 1.0f : 0.0f;
    if (b == 0 && t == 0) out[NB * MID] = (float)k;
}

// ================= Fallback chain (R6, known-good 67 us) =================
__global__ __launch_bounds__(256, 8) void k_gap(const float* __restrict__ x,
                                                float* __restrict__ gap) {
    const int r0 = blockIdx.x * 2;
    const int t  = threadIdx.x;
    const f32x4* p0 = (const f32x4*)(x + (size_t)r0 * HW);
    const f32x4* p1 = (const f32x4*)(x + (size_t)(r0 + 1) * HW);
    float a0 = 0.f, a1 = 0.f;
#pragma unroll
    for (int i = 0; i < 4; ++i) {
        f32x4 u = __builtin_nontemporal_load(&p0[i * 256 + t]);
        f32x4 v = __builtin_nontemporal_load(&p1[i * 256 + t]);
        a0 += (u.x + u.y) + (u.z + u.w);
        a1 += (v.x + v.y) + (v.z + v.w);
    }
    for (int off = 32; off; off >>= 1) {
        a0 += __shfl_down(a0, off, 64);
        a1 += __shfl_down(a1, off, 64);
    }
    __shared__ float w0[4], w1[4];
    const int wid = t >> 6, lane = t & 63;
    if (lane == 0) { w0[wid] = a0; w1[wid] = a1; }
    __syncthreads();
    if (t == 0) gap[r0]     = ((w0[0] + w0[1]) + (w0[2] + w0[3])) * (1.0f / HW);
    if (t == 1) gap[r0 + 1] = ((w1[0] + w1[1]) + (w1[2] + w1[3])) * (1.0f / HW);
}

__global__ __launch_bounds__(256) void k_fc1(const float* __restrict__ gap,
                                             const float* __restrict__ w1,
                                             const float* __restrict__ b1,
                                             float* __restrict__ h) {
    const int wid = threadIdx.x >> 6, lane = threadIdx.x & 63;
    const int o4 = (blockIdx.x * 4 + wid) * 4;
    const int b  = o4 >> 10;
    const int j0 = o4 & (MID2 - 1);
    const float* g = gap + b * CIN + lane * 8;
    const float4 g0 = *(const float4*)g;
    const float4 g1 = *(const float4*)(g + 4);
    float s[4];
#pragma unroll
    for (int r = 0; r < 4; ++r) {
        const float* w = w1 + (size_t)(j0 + r) * CIN + lane * 8;
        const float4 a = *(const float4*)w;
        const float4 c = *(const float4*)(w + 4);
        s[r] = (a.x * g0.x + a.y * g0.y) + (a.z * g0.z + a.w * g0.w) +
               (c.x * g1.x + c.y * g1.y) + (c.z * g1.z + c.w * g1.w);
    }
#pragma unroll
    for (int r = 0; r < 4; ++r)
        for (int off = 32; off; off >>= 1) s[r] += __shfl_down(s[r], off, 64);
    if (lane == 0) {
#pragma unroll
        for (int r = 0; r < 4; ++r) h[o4 + r] = fmaxf(s[r] + b1[j0 + r], 0.f);
    }
}

__global__ __launch_bounds__(256) void k_fc2(const float* __restrict__ h,
                                             const float* __restrict__ w2,
                                             const float* __restrict__ b2,
                                             float* __restrict__ scores) {
    const int wid = threadIdx.x >> 6, lane = threadIdx.x & 63;
    const int o4 = (blockIdx.x * 4 + wid) * 4;
    const int b  = o4 >> 9;
    const int m0 = o4 & (MID - 1);
    const float4* h4 = (const float4*)(h + b * MID2 + lane * 16);
    const float4 h0 = h4[0], h1 = h4[1], h2 = h4[2], h3 = h4[3];
    float s[4];
#pragma unroll
    for (int r = 0; r < 4; ++r) {
        const float4* w = (const float4*)(w2 + (size_t)(m0 + r) * MID2 + lane * 16);
        const float4 a = w[0], c = w[1], d = w[2], e = w[3];
        s[r] = (a.x * h0.x + a.y * h0.y) + (a.z * h0.z + a.w * h0.w) +
               (c.x * h1.x + c.y * h1.y) + (c.z * h1.z + c.w * h1.w) +
               (d.x * h2.x + d.y * h2.y) + (d.z * h2.z + d.w * h2.w) +
               (e.x * h3.x + e.y * h3.y) + (e.z * h3.z + e.w * h3.w);
    }
#pragma unroll
    for (int r = 0; r < 4; ++r)
        for (int off = 32; off; off >>= 1) s[r] += __shfl_down(s[r], off, 64);
    if (lane == 0) {
#pragma unroll
        for (int r = 0; r < 4; ++r) {
            const float v = s[r] + b2[m0 + r];
            scores[o4 + r] = 1.0f / (1.0f + __expf(-v));
        }
    }
}

__global__ __launch_bounds__(512) void k_mask(const float* __restrict__ scores,
                                              float* __restrict__ out) {
    __shared__ float srow[MID];
    __shared__ float red[8];
    __shared__ float thr;
    const int b = blockIdx.x, t = threadIdx.x;

    float s = 0.f;
#pragma unroll
    for (int i = 0; i < NB * MID / 512; ++i) s += scores[i * 512 + t];
    for (int off = 32; off; off >>= 1) s += __shfl_down(s, off, 64);
    const int wid = t >> 6, lane = t & 63;
    if (lane == 0) red[wid] = s;

    const float v = scores[b * MID + t];
    srow[t] = v;
    __syncthreads();

    const float tot = ((red[0] + red[1]) + (red[2] + red[3])) +
                      ((red[4] + red[5]) + (red[6] + red[7]));
    const float mean = tot / (float)(NB * MID);
    const float scale = fminf(fmaxf(mean, 0.25f), 1.0f);
    int k = (int)ceilf((float)MID * scale);
    k = min(max(k, 128), MID);

    const float4* srow4 = (const float4*)srow;
    int gt = 0, ge = 0;
    for (int i = 0; i < MID / 4; ++i) {
        const float4 u = srow4[i];
        gt += (u.x > v) + (u.y > v) + (u.z > v) + (u.w > v);
        ge += (u.x >= v) + (u.y >= v) + (u.z >= v) + (u.w >= v);
    }
    if (gt < k && ge >= k) thr = v;
    __syncthreads();
    out[b * MID + t] = (v >= thr) ? 1.0f : 0.0f;
    if (b == 0 && t == 0) out[NB * MID] = (float)k;
}

extern "C" void kernel_launch(void* const* d_in, const int* in_sizes, int n_in,
                              void* d_out, int out_size, void* d_ws, size_t ws_size,
                              hipStream_t stream) {
    const float* x  = (const float*)d_in[0];
    const float* w1 = (const float*)d_in[1];
    const float* b1 = (const float*)d_in[2];
    const float* w2 = (const float*)d_in[3];
    const float* b2 = (const float*)d_in[4];
    float* out = (float*)d_out;

    float* gap    = (float*)d_ws;            // NB*CIN  = 16384 floats
    float* h      = gap + NB * CIN;          // NB*MID2 = 32768 floats
    float* scores = h + NB * MID2;           // NB*MID  = 16384 floats

    // Capture-safe host queries: coop path only if FULL occupancy fits.
    int dev = 0;
    hipGetDevice(&dev);
    int coop = 0, ncu = 0, maxb = 0;
    hipDeviceGetAttribute(&coop, hipDeviceAttributeCooperativeLaunch, dev);
    hipDeviceGetAttribute(&ncu, hipDeviceAttributeMultiprocessorCount, dev);
    hipOccupancyMaxActiveBlocksPerMultiprocessor(&maxb, (const void*)k_all, 256, 0);

    hipError_t ret = hipErrorUnknown;
    if (coop && (long)maxb * ncu >= NBLK) {
        void* args[] = { (void*)&x, (void*)&w1, (void*)&b1, (void*)&w2, (void*)&b2,
                         (void*)&out, (void*)&gap, (void*)&h, (void*)&scores };
        ret = hipLaunchCooperativeKernel((const void*)k_all, dim3(NBLK), dim3(256),
                                         args, 0, stream);
    }
    if (ret != hipSuccess) {
        // Known-good 4-kernel chain fallback.
        k_gap <<<NB * CIN / 2,      256, 0, stream>>>(x, gap);
        k_fc1 <<<NB * MID2 / (4*4), 256, 0, stream>>>(gap, w1, b1, h);
        k_fc2 <<<NB * MID  / (4*4), 256, 0, stream>>>(h, w2, b2, scores);
        k_mask<<<NB,                512, 0, stream>>>(scores, out);
    }
}